// Round 1
// baseline (349.301 us; speedup 1.0000x reference)
//
#include <hip/hip_runtime.h>

#define BB 32
#define SS 2048
#define HH 1024
#define NCHUNK 32          // s-chunks per batch
#define ROWS_PER_CHUNK 64  // SS / NCHUNK
#define ROWS_PER_WAVE 16   // ROWS_PER_CHUNK / 4 waves

__device__ __forceinline__ float dot4(float4 a, float4 b) {
    return a.x * b.x + a.y * b.y + a.z * b.z + a.w * b.w;
}
__device__ __forceinline__ void fma4(float4& a, float p, float4 r) {
    a.x += p * r.x; a.y += p * r.y; a.z += p * r.z; a.w += p * r.w;
}
__device__ __forceinline__ void add4(float4& a, float4 r) {
    a.x += r.x; a.y += r.y; a.z += r.z; a.w += r.w;
}

// One block = (batch b, s-chunk). 4 waves; each wave owns 16 rows.
// Fused: score dot-product + exp + weighted row accumulation in one enc_hs read.
// Softmax shift-invariance: arg/bias terms are constant per batch -> cancel; no max
// subtraction needed (scores ~N(0,0.4^2), far from f32 exp overflow).
__global__ __launch_bounds__(256, 4) void attn_partial(
    const float* __restrict__ enc,   // [B,S,H]
    const int* __restrict__ mask,    // [B,S]  nonzero = masked
    const float* __restrict__ w1,    // [H+A], first H used
    const float* __restrict__ w2,
    float* __restrict__ pnum,        // [B,NCHUNK,2,H]
    float* __restrict__ pl)          // [B,NCHUNK,2]
{
    const int tid  = threadIdx.x;
    const int wave = tid >> 6;
    const int lane = tid & 63;
    const int b     = blockIdx.x / NCHUNK;
    const int chunk = blockIdx.x % NCHUNK;
    const int s0 = chunk * ROWS_PER_CHUNK + wave * ROWS_PER_WAVE;

    // register-resident weight fragments: lane covers float4 indices lane+64k
    const float4* w1v = (const float4*)w1;
    const float4* w2v = (const float4*)w2;
    float4 wa0 = w1v[lane], wa1 = w1v[lane + 64], wa2 = w1v[lane + 128], wa3 = w1v[lane + 192];
    float4 wb0 = w2v[lane], wb1 = w2v[lane + 64], wb2 = w2v[lane + 128], wb3 = w2v[lane + 192];

    float4 z = {0.f, 0.f, 0.f, 0.f};
    float4 a0 = z, a1 = z, a2 = z, a3 = z;   // ctx1 numerator fragments
    float4 c0 = z, c1 = z, c2 = z, c3 = z;   // ctx2 numerator fragments
    float l1 = 0.f, l2 = 0.f;                // denominators (wave-uniform)

    const int*    mrow = mask + (size_t)b * SS;
    const float4* encb = (const float4*)(enc + (size_t)b * SS * HH);

    for (int i = 0; i < ROWS_PER_WAVE; ++i) {
        const int s = s0 + i;
        if (mrow[s]) continue;  // masked row: zero weight, skip the 4 KiB load
        const float4* row = encb + (size_t)s * (HH / 4);
        float4 r0 = row[lane];
        float4 r1 = row[lane + 64];
        float4 r2 = row[lane + 128];
        float4 r3 = row[lane + 192];
        float d1 = dot4(r0, wa0) + dot4(r1, wa1) + dot4(r2, wa2) + dot4(r3, wa3);
        float d2 = dot4(r0, wb0) + dot4(r1, wb1) + dot4(r2, wb2) + dot4(r3, wb3);
#pragma unroll
        for (int off = 32; off; off >>= 1) {
            d1 += __shfl_xor(d1, off, 64);
            d2 += __shfl_xor(d2, off, 64);
        }
        const float p1 = __expf(d1);
        const float p2 = __expf(d2);
        l1 += p1; l2 += p2;
        fma4(a0, p1, r0); fma4(a1, p1, r1); fma4(a2, p1, r2); fma4(a3, p1, r3);
        fma4(c0, p2, r0); fma4(c1, p2, r1); fma4(c2, p2, r2); fma4(c3, p2, r3);
    }

    // cross-wave combine via LDS, one partial per block
    __shared__ float4 lds[4][2][HH / 4];  // 32 KiB
    __shared__ float  ldsl[4][2];
    lds[wave][0][lane]       = a0;
    lds[wave][0][lane + 64]  = a1;
    lds[wave][0][lane + 128] = a2;
    lds[wave][0][lane + 192] = a3;
    lds[wave][1][lane]       = c0;
    lds[wave][1][lane + 64]  = c1;
    lds[wave][1][lane + 128] = c2;
    lds[wave][1][lane + 192] = c3;
    if (lane == 0) { ldsl[wave][0] = l1; ldsl[wave][1] = l2; }
    __syncthreads();

    float4 s1 = lds[0][0][tid];
    add4(s1, lds[1][0][tid]); add4(s1, lds[2][0][tid]); add4(s1, lds[3][0][tid]);
    float4 s2 = lds[0][1][tid];
    add4(s2, lds[1][1][tid]); add4(s2, lds[2][1][tid]); add4(s2, lds[3][1][tid]);

    const size_t base = (size_t)(b * NCHUNK + chunk) * 2 * (HH / 4);
    float4* pv = (float4*)pnum;
    pv[base + tid]            = s1;
    pv[base + (HH / 4) + tid] = s2;
    if (tid < 2)
        pl[(b * NCHUNK + chunk) * 2 + tid] =
            ldsl[0][tid] + ldsl[1][tid] + ldsl[2][tid] + ldsl[3][tid];
}

// Combine chunk partials: out[b][j*H + h] = sum_c num / sum_c l
__global__ __launch_bounds__(256) void attn_combine(
    const float* __restrict__ pnum, const float* __restrict__ pl,
    float* __restrict__ out)
{
    const int b = blockIdx.x >> 1;
    const int j = blockIdx.x & 1;
    const int t = threadIdx.x;
    const float4* pv = (const float4*)pnum;
    float4 sum = {0.f, 0.f, 0.f, 0.f};
    float L = 0.f;
    for (int c = 0; c < NCHUNK; ++c) {
        const size_t base = (size_t)((b * NCHUNK + c) * 2 + j) * (HH / 4);
        add4(sum, pv[base + t]);
        L += pl[(b * NCHUNK + c) * 2 + j];
    }
    const float inv = 1.0f / L;
    float4 o = {sum.x * inv, sum.y * inv, sum.z * inv, sum.w * inv};
    ((float4*)out)[((size_t)b * 2 + j) * (HH / 4) + t] = o;
}

extern "C" void kernel_launch(void* const* d_in, const int* in_sizes, int n_in,
                              void* d_out, int out_size, void* d_ws, size_t ws_size,
                              hipStream_t stream) {
    // inputs: 0=arg1, 1=arg2, 2=enc_hs, 3=src_mask, 4=w1_w, 5=w1_b, 6=w2_w, 7=w2_b
    // arg1/arg2/biases/w[H:] cancel under softmax shift-invariance -> unread.
    const float* enc  = (const float*)d_in[2];
    const int*   mask = (const int*)d_in[3];
    const float* w1   = (const float*)d_in[4];
    const float* w2   = (const float*)d_in[6];
    float* out  = (float*)d_out;
    float* pnum = (float*)d_ws;                              // 8 MiB
    float* pl   = pnum + (size_t)BB * NCHUNK * 2 * HH;       // 8 KiB

    attn_partial<<<BB * NCHUNK, 256, 0, stream>>>(enc, mask, w1, w2, pnum, pl);
    attn_combine<<<BB * 2, 256, 0, stream>>>(pnum, pl, out);
}